// Round 2
// baseline (481.632 us; speedup 1.0000x reference)
//
#include <hip/hip_runtime.h>
#include <hip/hip_bf16.h>

#define T_TOK 2048
#define D_DIM 1024
#define H_DIM 2816
#define E_NUM 8
#define CAP   1024             // per-expert row capacity (mean load 512, ~24 sigma margin)

typedef __attribute__((ext_vector_type(8))) short short8;
typedef __attribute__((ext_vector_type(4))) float floatx4;

__device__ __forceinline__ unsigned short f2bf(float f) {
    unsigned int b = __float_as_uint(f);
    b += 0x7FFFu + ((b >> 16) & 1u);   // round-to-nearest-even
    return (unsigned short)(b >> 16);
}

// pack 2 f32 -> 2 bf16 in one v_perm (round-half-up via +0x8000)
__device__ __forceinline__ unsigned pk2(float lo, float hi) {
    unsigned a = __float_as_uint(lo) + 0x8000u;
    unsigned b = __float_as_uint(hi) + 0x8000u;
    return __builtin_amdgcn_perm(b, a, 0x07060302);
}

__device__ __forceinline__ short8 pack8r(float4 a, float4 b) {
    union { uint4 u; short8 s; } r;
    r.u.x = pk2(a.x, a.y);
    r.u.y = pk2(a.z, a.w);
    r.u.z = pk2(b.x, b.y);
    r.u.w = pk2(b.z, b.w);
    return r.s;
}

// async 16B global->LDS. LDS dest = wave-uniform base + lane*16.
__device__ __forceinline__ void gl2lds16(const void* g, void* l) {
    __builtin_amdgcn_global_load_lds(
        (const __attribute__((address_space(1))) unsigned int*)g,
        (__attribute__((address_space(3))) unsigned int*)l,
        16, 0, 0);
}

// Swizzled LDS tile layout (rows of 64 bf16 = 8 chunks of 16B), NO pad (dbuf fit):
//   byte(row, slot) = (row>>3)*1024 + (row&7)*128 + slot*16
//   content(row, slot) = global chunk (slot ^ (row&7)).
// Reads stay 2-way bank-aliased (free, m136) — same degree as padded layout.

// ---- fused gate: logits -> softmax -> top2 -> scatter-gather x into slots ----
__global__ __launch_bounds__(256) void k_gate2(const float* __restrict__ x,
                                               const float* __restrict__ Wg,
                                               int* __restrict__ stok,
                                               float* __restrict__ sw,
                                               int* __restrict__ counts,
                                               unsigned short* __restrict__ xg) {
    const int wave = threadIdx.x >> 6, lane = threadIdx.x & 63;
    const int t = blockIdx.x * 4 + wave;
    const float* xr = x + (size_t)t * D_DIM;
    float acc[E_NUM];
#pragma unroll
    for (int e = 0; e < E_NUM; ++e) acc[e] = 0.f;
#pragma unroll 4
    for (int i = 0; i < D_DIM / 64; ++i) {
        float xv = xr[lane + 64 * i];
#pragma unroll
        for (int e = 0; e < E_NUM; ++e) acc[e] += xv * Wg[e * D_DIM + lane + 64 * i];
    }
#pragma unroll
    for (int e = 0; e < E_NUM; ++e) {
#pragma unroll
        for (int s = 32; s > 0; s >>= 1) acc[e] += __shfl_xor(acc[e], s, 64);
    }
    int slot0 = 0, slot1 = 0;
    if (lane == 0) {
        float mx = acc[0];
#pragma unroll
        for (int e = 1; e < E_NUM; ++e) mx = fmaxf(mx, acc[e]);
        float p[E_NUM], s = 0.f;
#pragma unroll
        for (int e = 0; e < E_NUM; ++e) { p[e] = __expf(acc[e] - mx); s += p[e]; }
        int i0 = 0;
#pragma unroll
        for (int e = 1; e < E_NUM; ++e) if (p[e] > p[i0]) i0 = e;
        int i1 = (i0 == 0) ? 1 : 0;
#pragma unroll
        for (int e = 0; e < E_NUM; ++e) if (e != i0 && p[e] > p[i1]) i1 = e;
        float s0 = p[i0] / s, s1 = p[i1] / s;
        float d = s0 + s1 + 1e-20f;
        int p0 = atomicAdd(&counts[i0], 1); if (p0 >= CAP) p0 = CAP - 1;
        int p1 = atomicAdd(&counts[i1], 1); if (p1 >= CAP) p1 = CAP - 1;
        slot0 = i0 * CAP + p0;
        slot1 = i1 * CAP + p1;
        stok[slot0] = t; sw[slot0] = s0 / d;
        stok[slot1] = t; sw[slot1] = s1 / d;
    }
    slot0 = __shfl(slot0, 0, 64);
    slot1 = __shfl(slot1, 0, 64);
    const float4* xr4 = (const float4*)xr;
    ushort4* xg4 = (ushort4*)xg;
#pragma unroll
    for (int it = 0; it < 4; ++it) {
        float4 v = xr4[lane + 64 * it];
        ushort4 o;
        o.x = f2bf(v.x); o.y = f2bf(v.y); o.z = f2bf(v.z); o.w = f2bf(v.w);
        xg4[(size_t)slot0 * 256 + lane + 64 * it] = o;
        xg4[(size_t)slot1 * 256 + lane + 64 * it] = o;
    }
}

// ---- compute one staged K-tile for GEMM 1&3 ----
__device__ __forceinline__ void g13_tile(const unsigned char* Ab, const unsigned char* B1b,
                                         const unsigned char* B3b, int agrp, int c0, int c1,
                                         int f8, int f7,
                                         floatx4 (&acc1)[4][2], floatx4 (&acc3)[4][2]) {
    short8 b1f[2][2], b3f[2][2];
#pragma unroll
    for (int n = 0; n < 2; ++n) {
        const int bg = (n * 2 + f8) * 1024 + f7 * 128;
        b1f[n][0] = *(const short8*)(B1b + bg + c0);
        b1f[n][1] = *(const short8*)(B1b + bg + c1);
        b3f[n][0] = *(const short8*)(B3b + bg + c0);
        b3f[n][1] = *(const short8*)(B3b + bg + c1);
    }
#pragma unroll
    for (int m = 0; m < 4; ++m) {
        const unsigned char* ab = Ab + agrp + m * 2048;
        short8 a0 = *(const short8*)(ab + c0);
        short8 a1 = *(const short8*)(ab + c1);
#pragma unroll
        for (int n = 0; n < 2; ++n) {
            acc1[m][n] = __builtin_amdgcn_mfma_f32_16x16x32_bf16(a0, b1f[n][0], acc1[m][n], 0, 0, 0);
            acc1[m][n] = __builtin_amdgcn_mfma_f32_16x16x32_bf16(a1, b1f[n][1], acc1[m][n], 0, 0, 0);
            acc3[m][n] = __builtin_amdgcn_mfma_f32_16x16x32_bf16(a0, b3f[n][0], acc3[m][n], 0, 0, 0);
            acc3[m][n] = __builtin_amdgcn_mfma_f32_16x16x32_bf16(a1, b3f[n][1], acc3[m][n], 0, 0, 0);
        }
    }
}

// ---- GEMM 1&3: BM=256, BN=32(W1)+32(W3), BK=64, double-buffered 2-phase pipeline ----
__global__ __launch_bounds__(256, 2) void k_gemm13(const unsigned short* __restrict__ xg,
                                                   const float* __restrict__ W1,
                                                   const float* __restrict__ W3,
                                                   const int* __restrict__ counts,
                                                   unsigned short* __restrict__ U) {
    const int nt = blockIdx.x;       // H/32 = 88
    const int mt = blockIdx.y;       // CAP/256 = 4
    const int e  = blockIdx.z;
    const int cnt = min(counts[e], CAP);
    if (mt * 256 >= cnt) return;

    __shared__ __align__(16) unsigned char As[2][32768];   // 256 rows x 64 bf16, x2 buffers
    __shared__ __align__(16) unsigned char B1s[2][4096];   // 32 rows x 64 bf16, x2
    __shared__ __align__(16) unsigned char B3s[2][4096];

    const int tid = threadIdx.x, lane = tid & 63, wave = tid >> 6;
    const int fr = lane & 15, quad = lane >> 4, f7 = fr & 7, f8 = fr >> 3;

    const unsigned short* aBase = xg
        + ((size_t)e * CAP + mt * 256 + wave * 64 + (lane >> 3)) * D_DIM
        + ((lane & 7) ^ (lane >> 3)) * 8;

    const int br = tid >> 3, bc = tid & 7;
    const float* w1p = W1 + ((size_t)e * H_DIM + nt * 32 + br) * D_DIM + bc * 8;
    const float* w3p = W3 + ((size_t)e * H_DIM + nt * 32 + br) * D_DIM + bc * 8;
    const int bslot = (br >> 3) * 1024 + (br & 7) * 128 + ((bc ^ (br & 7)) << 4);

    floatx4 acc1[4][2], acc3[4][2];
#pragma unroll
    for (int m = 0; m < 4; ++m)
#pragma unroll
        for (int n = 0; n < 2; ++n) { acc1[m][n] = (floatx4)0.f; acc3[m][n] = (floatx4)0.f; }

    const int agrp = (wave * 8 + f8) * 1024 + f7 * 128;
    const int c0 = (quad ^ f7) << 4;          // kk=0 chunk byte offset
    const int c1 = ((4 | quad) ^ f7) << 4;    // kk=1

    // ---- prologue: stage tile 0 into buffer 0 ----
#pragma unroll
    for (int j = 0; j < 8; ++j)
        gl2lds16(aBase + (size_t)j * 8 * D_DIM, As[0] + (wave * 8 + j) * 1024);
    {
        float4 u0 = *(const float4*)(w1p);
        float4 u1 = *(const float4*)(w1p + 4);
        float4 v0 = *(const float4*)(w3p);
        float4 v1 = *(const float4*)(w3p + 4);
        *(short8*)(B1s[0] + bslot) = pack8r(u0, u1);
        *(short8*)(B3s[0] + bslot) = pack8r(v0, v1);
    }
    __syncthreads();

    int cur = 0;
#pragma unroll 1
    for (int t = 0; t < D_DIM / 64 - 1; ++t) {
        const int kn = (t + 1) * 64;
        // issue async A-stage for next tile into the other buffer
#pragma unroll
        for (int j = 0; j < 8; ++j)
            gl2lds16(aBase + (size_t)j * 8 * D_DIM + kn, As[cur ^ 1] + (wave * 8 + j) * 1024);
        // issue next-tile B loads (f32 -> regs); consumed after the MFMA block
        float4 u0 = *(const float4*)(w1p + kn);
        float4 u1 = *(const float4*)(w1p + kn + 4);
        float4 v0 = *(const float4*)(w3p + kn);
        float4 v1 = *(const float4*)(w3p + kn + 4);

        // compute current tile (hides the latency of the loads above)
        g13_tile(As[cur], B1s[cur], B3s[cur], agrp, c0, c1, f8, f7, acc1, acc3);

        // write next-tile B into the other buffer
        *(short8*)(B1s[cur ^ 1] + bslot) = pack8r(u0, u1);
        *(short8*)(B3s[cur ^ 1] + bslot) = pack8r(v0, v1);
        __syncthreads();   // drains gl2lds + orders dbuf handoff (single barrier/K-step)
        cur ^= 1;
    }
    // epilogue tile
    g13_tile(As[cur], B1s[cur], B3s[cur], agrp, c0, c1, f8, f7, acc1, acc3);

#pragma unroll
    for (int m = 0; m < 4; ++m) {
#pragma unroll
        for (int r = 0; r < 4; ++r) {
            int g = mt * 256 + wave * 64 + m * 16 + quad * 4 + r;
            if (g < cnt) {
                size_t rowb = ((size_t)e * CAP + g) * H_DIM + nt * 32;
#pragma unroll
                for (int n = 0; n < 2; ++n) {
                    float u1v = acc1[m][n][r], u3v = acc3[m][n][r];
                    float u = u1v / (1.f + __expf(-u1v)) * u3v;
                    U[rowb + n * 16 + fr] = f2bf(u);
                }
            }
        }
    }
}

// ---- compute one staged K-tile for GEMM 2 (BN=64) ----
__device__ __forceinline__ void g2_tile(const unsigned char* Ab, const unsigned char* Bb,
                                        int agrp, int c0, int c1, int f8, int f7,
                                        floatx4 (&acc)[4][4]) {
    short8 bf[4][2];
#pragma unroll
    for (int n = 0; n < 4; ++n) {
        const int bg = (n * 2 + f8) * 1024 + f7 * 128;
        bf[n][0] = *(const short8*)(Bb + bg + c0);
        bf[n][1] = *(const short8*)(Bb + bg + c1);
    }
#pragma unroll
    for (int m = 0; m < 4; ++m) {
        const unsigned char* ab = Ab + agrp + m * 2048;
        short8 a0 = *(const short8*)(ab + c0);
        short8 a1 = *(const short8*)(ab + c1);
#pragma unroll
        for (int n = 0; n < 4; ++n) {
            acc[m][n] = __builtin_amdgcn_mfma_f32_16x16x32_bf16(a0, bf[n][0], acc[m][n], 0, 0, 0);
            acc[m][n] = __builtin_amdgcn_mfma_f32_16x16x32_bf16(a1, bf[n][1], acc[m][n], 0, 0, 0);
        }
    }
}

// ---- GEMM 2: BM=256, BN=64, BK=64, K=2816; dbuf 2-phase; fused weighted atomic epilogue ----
__global__ __launch_bounds__(256, 2) void k_gemm2(const unsigned short* __restrict__ U,
                                                  const float* __restrict__ W2,
                                                  const int* __restrict__ counts,
                                                  const int* __restrict__ stok,
                                                  const float* __restrict__ sw,
                                                  float* __restrict__ y) {
    const int nt = blockIdx.x;       // D/64 = 16
    const int mt = blockIdx.y;       // CAP/256 = 4
    const int e  = blockIdx.z;
    const int cnt = min(counts[e], CAP);
    if (mt * 256 >= cnt) return;

    __shared__ __align__(16) unsigned char As[2][32768];   // 256 rows x 64 bf16, x2
    __shared__ __align__(16) unsigned char Bs[2][8192];    // 64 w-rows x 64 bf16, x2

    const int tid = threadIdx.x, lane = tid & 63, wave = tid >> 6;
    const int fr = lane & 15, quad = lane >> 4, f7 = fr & 7, f8 = fr >> 3;

    const unsigned short* aBase = U
        + ((size_t)e * CAP + mt * 256 + wave * 64 + (lane >> 3)) * H_DIM
        + ((lane & 7) ^ (lane >> 3)) * 8;

    const int br = tid >> 3, bc = tid & 7;       // rows br and br+32, chunk col bc
    const float* w2p0 = W2 + ((size_t)e * D_DIM + nt * 64 + br) * H_DIM + bc * 8;
    const float* w2p1 = w2p0 + (size_t)32 * H_DIM;
    const int bslot0 = (br >> 3) * 1024 + (br & 7) * 128 + ((bc ^ (br & 7)) << 4);
    const int bslot1 = bslot0 + 4096;            // (row+32)>>3 = +4 groups

    floatx4 acc[4][4];
#pragma unroll
    for (int m = 0; m < 4; ++m)
#pragma unroll
        for (int n = 0; n < 4; ++n) acc[m][n] = (floatx4)0.f;

    const int agrp = (wave * 8 + f8) * 1024 + f7 * 128;
    const int c0 = (quad ^ f7) << 4;
    const int c1 = ((4 | quad) ^ f7) << 4;

    // ---- prologue: stage tile 0 into buffer 0 ----
#pragma unroll
    for (int j = 0; j < 8; ++j)
        gl2lds16(aBase + (size_t)j * 8 * H_DIM, As[0] + (wave * 8 + j) * 1024);
    {
        float4 u0 = *(const float4*)(w2p0);
        float4 u1 = *(const float4*)(w2p0 + 4);
        float4 v0 = *(const float4*)(w2p1);
        float4 v1 = *(const float4*)(w2p1 + 4);
        *(short8*)(Bs[0] + bslot0) = pack8r(u0, u1);
        *(short8*)(Bs[0] + bslot1) = pack8r(v0, v1);
    }
    __syncthreads();

    int cur = 0;
#pragma unroll 1
    for (int t = 0; t < H_DIM / 64 - 1; ++t) {
        const int kn = (t + 1) * 64;
#pragma unroll
        for (int j = 0; j < 8; ++j)
            gl2lds16(aBase + (size_t)j * 8 * H_DIM + kn, As[cur ^ 1] + (wave * 8 + j) * 1024);
        float4 u0 = *(const float4*)(w2p0 + kn);
        float4 u1 = *(const float4*)(w2p0 + kn + 4);
        float4 v0 = *(const float4*)(w2p1 + kn);
        float4 v1 = *(const float4*)(w2p1 + kn + 4);

        g2_tile(As[cur], Bs[cur], agrp, c0, c1, f8, f7, acc);

        *(short8*)(Bs[cur ^ 1] + bslot0) = pack8r(u0, u1);
        *(short8*)(Bs[cur ^ 1] + bslot1) = pack8r(v0, v1);
        __syncthreads();
        cur ^= 1;
    }
    g2_tile(As[cur], Bs[cur], agrp, c0, c1, f8, f7, acc);

#pragma unroll
    for (int m = 0; m < 4; ++m) {
#pragma unroll
        for (int r = 0; r < 4; ++r) {
            int g = mt * 256 + wave * 64 + m * 16 + quad * 4 + r;
            if (g < cnt) {
                int slot = e * CAP + g;
                int t = stok[slot];
                float w = sw[slot];
                float* yr = y + (size_t)t * D_DIM + nt * 64;
#pragma unroll
                for (int n = 0; n < 4; ++n)
                    atomicAdd(&yr[n * 16 + fr], w * acc[m][n][r]);
            }
        }
    }
}

// ---------------- workspace layout ----------------
static const size_t OFF_XG   = 0;                                   // 8*CAP*D*2 = 16,777,216
static const size_t OFF_U    = (size_t)E_NUM * CAP * D_DIM * 2;     // 8*CAP*H*2 = 46,137,344
static const size_t OFF_STOK = OFF_U + (size_t)E_NUM * CAP * H_DIM * 2;
static const size_t OFF_SW   = OFF_STOK + (size_t)E_NUM * CAP * 4;
static const size_t OFF_META = OFF_SW + (size_t)E_NUM * CAP * 4;

extern "C" void kernel_launch(void* const* d_in, const int* in_sizes, int n_in,
                              void* d_out, int out_size, void* d_ws, size_t ws_size,
                              hipStream_t stream) {
    const float* x  = (const float*)d_in[0];
    const float* Wg = (const float*)d_in[1];
    const float* W1 = (const float*)d_in[2];
    const float* W2 = (const float*)d_in[3];
    const float* W3 = (const float*)d_in[4];
    float* y = (float*)d_out;
    char* ws = (char*)d_ws;

    unsigned short* xg = (unsigned short*)(ws + OFF_XG);
    unsigned short* U  = (unsigned short*)(ws + OFF_U);
    int*   stok   = (int*)(ws + OFF_STOK);
    float* sw     = (float*)(ws + OFF_SW);
    int*   counts = (int*)(ws + OFF_META);

    hipMemsetAsync(counts, 0, 64, stream);
    hipMemsetAsync(y, 0, (size_t)T_TOK * D_DIM * sizeof(float), stream);

    k_gate2<<<T_TOK / 4, 256, 0, stream>>>(x, Wg, stok, sw, counts, xg);
    k_gemm13<<<dim3(H_DIM / 32, CAP / 256, E_NUM), 256, 0, stream>>>(xg, W1, W3, counts, U);
    k_gemm2<<<dim3(D_DIM / 64, CAP / 256, E_NUM), 256, 0, stream>>>(U, W2, counts, stok, sw, y);
}

// Round 3
// 431.214 us; speedup vs baseline: 1.1169x; 1.1169x over previous
//
#include <hip/hip_runtime.h>
#include <hip/hip_bf16.h>

#define T_TOK 2048
#define D_DIM 1024
#define H_DIM 2816
#define E_NUM 8
#define CAP   1024             // per-expert row capacity (mean load 512, ~24 sigma margin)

typedef __attribute__((ext_vector_type(8))) short short8;
typedef __attribute__((ext_vector_type(4))) float floatx4;

__device__ __forceinline__ unsigned short f2bf(float f) {
    unsigned int b = __float_as_uint(f);
    b += 0x7FFFu + ((b >> 16) & 1u);   // round-to-nearest-even
    return (unsigned short)(b >> 16);
}

// pack 2 f32 -> 2 bf16 in one v_perm (round-half-up via +0x8000)
__device__ __forceinline__ unsigned pk2(float lo, float hi) {
    unsigned a = __float_as_uint(lo) + 0x8000u;
    unsigned b = __float_as_uint(hi) + 0x8000u;
    return __builtin_amdgcn_perm(b, a, 0x07060302);
}

__device__ __forceinline__ short8 pack8r(float4 a, float4 b) {
    union { uint4 u; short8 s; } r;
    r.u.x = pk2(a.x, a.y);
    r.u.y = pk2(a.z, a.w);
    r.u.z = pk2(b.x, b.y);
    r.u.w = pk2(b.z, b.w);
    return r.s;
}

// async 16B global->LDS. LDS dest = wave-uniform base + lane*16.
__device__ __forceinline__ void gl2lds16(const void* g, void* l) {
    __builtin_amdgcn_global_load_lds(
        (const __attribute__((address_space(1))) unsigned int*)g,
        (__attribute__((address_space(3))) unsigned int*)l,
        16, 0, 0);
}

// Swizzled LDS tile layout (rows of 64 bf16 = 8 chunks of 16B), unpadded:
//   byte(row, slot) = (row>>3)*1024 + (row&7)*128 + slot*16
//   content(row, slot) = global chunk (slot ^ (row&7)).
// Measured 0 bank conflicts (round 2).
// Pipeline: read-frags-first single-buffer. All ds_reads of tile t complete
// before the barrier; gl2lds(t+1) is issued after it and drains at the
// post-MFMA barrier, so HBM/L3 latency hides under the 32-MFMA block.

// ---- fused gate: logits -> softmax -> top2 -> scatter-gather x into slots ----
__global__ __launch_bounds__(256) void k_gate2(const float* __restrict__ x,
                                               const float* __restrict__ Wg,
                                               int* __restrict__ stok,
                                               float* __restrict__ sw,
                                               int* __restrict__ counts,
                                               unsigned short* __restrict__ xg) {
    const int wave = threadIdx.x >> 6, lane = threadIdx.x & 63;
    const int t = blockIdx.x * 4 + wave;
    const float* xr = x + (size_t)t * D_DIM;
    float acc[E_NUM];
#pragma unroll
    for (int e = 0; e < E_NUM; ++e) acc[e] = 0.f;
#pragma unroll 4
    for (int i = 0; i < D_DIM / 64; ++i) {
        float xv = xr[lane + 64 * i];
#pragma unroll
        for (int e = 0; e < E_NUM; ++e) acc[e] += xv * Wg[e * D_DIM + lane + 64 * i];
    }
#pragma unroll
    for (int e = 0; e < E_NUM; ++e) {
#pragma unroll
        for (int s = 32; s > 0; s >>= 1) acc[e] += __shfl_xor(acc[e], s, 64);
    }
    int slot0 = 0, slot1 = 0;
    if (lane == 0) {
        float mx = acc[0];
#pragma unroll
        for (int e = 1; e < E_NUM; ++e) mx = fmaxf(mx, acc[e]);
        float p[E_NUM], s = 0.f;
#pragma unroll
        for (int e = 0; e < E_NUM; ++e) { p[e] = __expf(acc[e] - mx); s += p[e]; }
        int i0 = 0;
#pragma unroll
        for (int e = 1; e < E_NUM; ++e) if (p[e] > p[i0]) i0 = e;
        int i1 = (i0 == 0) ? 1 : 0;
#pragma unroll
        for (int e = 0; e < E_NUM; ++e) if (e != i0 && p[e] > p[i1]) i1 = e;
        float s0 = p[i0] / s, s1 = p[i1] / s;
        float d = s0 + s1 + 1e-20f;
        int p0 = atomicAdd(&counts[i0], 1); if (p0 >= CAP) p0 = CAP - 1;
        int p1 = atomicAdd(&counts[i1], 1); if (p1 >= CAP) p1 = CAP - 1;
        slot0 = i0 * CAP + p0;
        slot1 = i1 * CAP + p1;
        stok[slot0] = t; sw[slot0] = s0 / d;
        stok[slot1] = t; sw[slot1] = s1 / d;
    }
    slot0 = __shfl(slot0, 0, 64);
    slot1 = __shfl(slot1, 0, 64);
    const float4* xr4 = (const float4*)xr;
    ushort4* xg4 = (ushort4*)xg;
#pragma unroll
    for (int it = 0; it < 4; ++it) {
        float4 v = xr4[lane + 64 * it];
        ushort4 o;
        o.x = f2bf(v.x); o.y = f2bf(v.y); o.z = f2bf(v.z); o.w = f2bf(v.w);
        xg4[(size_t)slot0 * 256 + lane + 64 * it] = o;
        xg4[(size_t)slot1 * 256 + lane + 64 * it] = o;
    }
}

// ---- GEMM 1&3: BM=256, BN=32(W1)+32(W3), BK=64, read-first single-buffer pipeline ----
__global__ __launch_bounds__(256, 2) void k_gemm13(const unsigned short* __restrict__ xg,
                                                   const float* __restrict__ W1,
                                                   const float* __restrict__ W3,
                                                   const int* __restrict__ counts,
                                                   unsigned short* __restrict__ U) {
    const int nt = blockIdx.x;       // H/32 = 88
    const int mt = blockIdx.y;       // CAP/256 = 4
    const int e  = blockIdx.z;
    const int cnt = min(counts[e], CAP);
    if (mt * 256 >= cnt) return;

    __shared__ __align__(16) unsigned char As[32768];   // 256 rows x 64 bf16
    __shared__ __align__(16) unsigned char B1s[4096];   // 32 rows x 64 bf16
    __shared__ __align__(16) unsigned char B3s[4096];

    const int tid = threadIdx.x, lane = tid & 63, wave = tid >> 6;
    const int fr = lane & 15, quad = lane >> 4, f7 = fr & 7, f8 = fr >> 3;

    const unsigned short* aBase = xg
        + ((size_t)e * CAP + mt * 256 + wave * 64 + (lane >> 3)) * D_DIM
        + ((lane & 7) ^ (lane >> 3)) * 8;

    const int br = tid >> 3, bc = tid & 7;
    const float* w1p = W1 + ((size_t)e * H_DIM + nt * 32 + br) * D_DIM + bc * 8;
    const float* w3p = W3 + ((size_t)e * H_DIM + nt * 32 + br) * D_DIM + bc * 8;
    const int bslot = (br >> 3) * 1024 + (br & 7) * 128 + ((bc ^ (br & 7)) << 4);

    floatx4 acc1[4][2], acc3[4][2];
#pragma unroll
    for (int m = 0; m < 4; ++m)
#pragma unroll
        for (int n = 0; n < 2; ++n) { acc1[m][n] = (floatx4)0.f; acc3[m][n] = (floatx4)0.f; }

    const int agrp = (wave * 8 + f8) * 1024 + f7 * 128;
    const int c0 = (quad ^ f7) << 4;          // kk=0 chunk byte offset
    const int c1 = ((4 | quad) ^ f7) << 4;    // kk=1

    // ---- prologue: stage tile 0 ----
#pragma unroll
    for (int j = 0; j < 8; ++j)
        gl2lds16(aBase + (size_t)j * 8 * D_DIM, As + (wave * 8 + j) * 1024);
    {
        float4 u0 = *(const float4*)(w1p);
        float4 u1 = *(const float4*)(w1p + 4);
        float4 v0 = *(const float4*)(w3p);
        float4 v1 = *(const float4*)(w3p + 4);
        *(short8*)(B1s + bslot) = pack8r(u0, u1);
        *(short8*)(B3s + bslot) = pack8r(v0, v1);
    }
    __syncthreads();

#pragma unroll 1
    for (int t = 0; t < D_DIM / 64; ++t) {
        // ---- read ALL fragments of tile t into registers ----
        short8 a[4][2], b1[2][2], b3[2][2];
#pragma unroll
        for (int m = 0; m < 4; ++m) {
            const unsigned char* ab = As + agrp + m * 2048;
            a[m][0] = *(const short8*)(ab + c0);
            a[m][1] = *(const short8*)(ab + c1);
        }
#pragma unroll
        for (int n = 0; n < 2; ++n) {
            const int bg = (n * 2 + f8) * 1024 + f7 * 128;
            b1[n][0] = *(const short8*)(B1s + bg + c0);
            b1[n][1] = *(const short8*)(B1s + bg + c1);
            b3[n][0] = *(const short8*)(B3s + bg + c0);
            b3[n][1] = *(const short8*)(B3s + bg + c1);
        }
        __syncthreads();   // all waves done reading tile t (lgkm drained by sync)

        const bool more = (t < D_DIM / 64 - 1);
        float4 u0, u1, v0, v1;
        if (more) {
            const int kn = (t + 1) * 64;
            // issue async A-stage for tile t+1 (drains at next barrier, under MFMA)
#pragma unroll
            for (int j = 0; j < 8; ++j)
                gl2lds16(aBase + (size_t)j * 8 * D_DIM + kn, As + (wave * 8 + j) * 1024);
            u0 = *(const float4*)(w1p + kn);
            u1 = *(const float4*)(w1p + kn + 4);
            v0 = *(const float4*)(w3p + kn);
            v1 = *(const float4*)(w3p + kn + 4);
        }

        // ---- 32 MFMAs on registers (covers the load latency above) ----
#pragma unroll
        for (int m = 0; m < 4; ++m) {
#pragma unroll
            for (int n = 0; n < 2; ++n) {
                acc1[m][n] = __builtin_amdgcn_mfma_f32_16x16x32_bf16(a[m][0], b1[n][0], acc1[m][n], 0, 0, 0);
                acc1[m][n] = __builtin_amdgcn_mfma_f32_16x16x32_bf16(a[m][1], b1[n][1], acc1[m][n], 0, 0, 0);
                acc3[m][n] = __builtin_amdgcn_mfma_f32_16x16x32_bf16(a[m][0], b3[n][0], acc3[m][n], 0, 0, 0);
                acc3[m][n] = __builtin_amdgcn_mfma_f32_16x16x32_bf16(a[m][1], b3[n][1], acc3[m][n], 0, 0, 0);
            }
        }

        if (more) {
            *(short8*)(B1s + bslot) = pack8r(u0, u1);
            *(short8*)(B3s + bslot) = pack8r(v0, v1);
            __syncthreads();   // drains gl2lds (vmcnt) + B writes; tile t+1 ready
        }
    }

#pragma unroll
    for (int m = 0; m < 4; ++m) {
#pragma unroll
        for (int r = 0; r < 4; ++r) {
            int g = mt * 256 + wave * 64 + m * 16 + quad * 4 + r;
            if (g < cnt) {
                size_t rowb = ((size_t)e * CAP + g) * H_DIM + nt * 32;
#pragma unroll
                for (int n = 0; n < 2; ++n) {
                    float u1v = acc1[m][n][r], u3v = acc3[m][n][r];
                    float u = u1v / (1.f + __expf(-u1v)) * u3v;
                    U[rowb + n * 16 + fr] = f2bf(u);
                }
            }
        }
    }
}

// ---- GEMM 2: BM=256, BN=64, BK=64, K=2816; read-first single-buffer pipeline ----
__global__ __launch_bounds__(256, 2) void k_gemm2(const unsigned short* __restrict__ U,
                                                  const float* __restrict__ W2,
                                                  const int* __restrict__ counts,
                                                  const int* __restrict__ stok,
                                                  const float* __restrict__ sw,
                                                  float* __restrict__ y) {
    const int nt = blockIdx.x;       // D/64 = 16
    const int mt = blockIdx.y;       // CAP/256 = 4
    const int e  = blockIdx.z;
    const int cnt = min(counts[e], CAP);
    if (mt * 256 >= cnt) return;

    __shared__ __align__(16) unsigned char As[32768];   // 256 rows x 64 bf16
    __shared__ __align__(16) unsigned char Bs[8192];    // 64 w-rows x 64 bf16

    const int tid = threadIdx.x, lane = tid & 63, wave = tid >> 6;
    const int fr = lane & 15, quad = lane >> 4, f7 = fr & 7, f8 = fr >> 3;

    const unsigned short* aBase = U
        + ((size_t)e * CAP + mt * 256 + wave * 64 + (lane >> 3)) * H_DIM
        + ((lane & 7) ^ (lane >> 3)) * 8;

    const int br = tid >> 3, bc = tid & 7;       // rows br and br+32, chunk col bc
    const float* w2p0 = W2 + ((size_t)e * D_DIM + nt * 64 + br) * H_DIM + bc * 8;
    const float* w2p1 = w2p0 + (size_t)32 * H_DIM;
    const int bslot0 = (br >> 3) * 1024 + (br & 7) * 128 + ((bc ^ (br & 7)) << 4);
    const int bslot1 = bslot0 + 4096;            // (row+32)>>3 = +4 groups

    floatx4 acc[4][4];
#pragma unroll
    for (int m = 0; m < 4; ++m)
#pragma unroll
        for (int n = 0; n < 4; ++n) acc[m][n] = (floatx4)0.f;

    const int agrp = (wave * 8 + f8) * 1024 + f7 * 128;
    const int c0 = (quad ^ f7) << 4;
    const int c1 = ((4 | quad) ^ f7) << 4;

    // ---- prologue: stage tile 0 ----
#pragma unroll
    for (int j = 0; j < 8; ++j)
        gl2lds16(aBase + (size_t)j * 8 * H_DIM, As + (wave * 8 + j) * 1024);
    {
        float4 u0 = *(const float4*)(w2p0);
        float4 u1 = *(const float4*)(w2p0 + 4);
        float4 v0 = *(const float4*)(w2p1);
        float4 v1 = *(const float4*)(w2p1 + 4);
        *(short8*)(Bs + bslot0) = pack8r(u0, u1);
        *(short8*)(Bs + bslot1) = pack8r(v0, v1);
    }
    __syncthreads();

#pragma unroll 1
    for (int t = 0; t < H_DIM / 64; ++t) {
        // ---- read ALL fragments of tile t into registers ----
        short8 a[4][2], bf[4][2];
#pragma unroll
        for (int m = 0; m < 4; ++m) {
            const unsigned char* ab = As + agrp + m * 2048;
            a[m][0] = *(const short8*)(ab + c0);
            a[m][1] = *(const short8*)(ab + c1);
        }
#pragma unroll
        for (int n = 0; n < 4; ++n) {
            const int bg = (n * 2 + f8) * 1024 + f7 * 128;
            bf[n][0] = *(const short8*)(Bs + bg + c0);
            bf[n][1] = *(const short8*)(Bs + bg + c1);
        }
        __syncthreads();   // all waves done reading tile t

        const bool more = (t < H_DIM / 64 - 1);
        float4 u0, u1, v0, v1;
        if (more) {
            const int kn = (t + 1) * 64;
#pragma unroll
            for (int j = 0; j < 8; ++j)
                gl2lds16(aBase + (size_t)j * 8 * H_DIM + kn, As + (wave * 8 + j) * 1024);
            u0 = *(const float4*)(w2p0 + kn);
            u1 = *(const float4*)(w2p0 + kn + 4);
            v0 = *(const float4*)(w2p1 + kn);
            v1 = *(const float4*)(w2p1 + kn + 4);
        }

        // ---- 32 MFMAs on registers ----
#pragma unroll
        for (int m = 0; m < 4; ++m) {
#pragma unroll
            for (int n = 0; n < 4; ++n) {
                acc[m][n] = __builtin_amdgcn_mfma_f32_16x16x32_bf16(a[m][0], bf[n][0], acc[m][n], 0, 0, 0);
                acc[m][n] = __builtin_amdgcn_mfma_f32_16x16x32_bf16(a[m][1], bf[n][1], acc[m][n], 0, 0, 0);
            }
        }

        if (more) {
            *(short8*)(Bs + bslot0) = pack8r(u0, u1);
            *(short8*)(Bs + bslot1) = pack8r(v0, v1);
            __syncthreads();   // drains gl2lds + B writes; tile t+1 ready
        }
    }

#pragma unroll
    for (int m = 0; m < 4; ++m) {
#pragma unroll
        for (int r = 0; r < 4; ++r) {
            int g = mt * 256 + wave * 64 + m * 16 + quad * 4 + r;
            if (g < cnt) {
                int slot = e * CAP + g;
                int t = stok[slot];
                float w = sw[slot];
                float* yr = y + (size_t)t * D_DIM + nt * 64;
#pragma unroll
                for (int n = 0; n < 4; ++n)
                    atomicAdd(&yr[n * 16 + fr], w * acc[m][n][r]);
            }
        }
    }
}

// ---------------- workspace layout ----------------
static const size_t OFF_XG   = 0;                                   // 8*CAP*D*2 = 16,777,216
static const size_t OFF_U    = (size_t)E_NUM * CAP * D_DIM * 2;     // 8*CAP*H*2 = 46,137,344
static const size_t OFF_STOK = OFF_U + (size_t)E_NUM * CAP * H_DIM * 2;
static const size_t OFF_SW   = OFF_STOK + (size_t)E_NUM * CAP * 4;
static const size_t OFF_META = OFF_SW + (size_t)E_NUM * CAP * 4;

extern "C" void kernel_launch(void* const* d_in, const int* in_sizes, int n_in,
                              void* d_out, int out_size, void* d_ws, size_t ws_size,
                              hipStream_t stream) {
    const float* x  = (const float*)d_in[0];
    const float* Wg = (const float*)d_in[1];
    const float* W1 = (const float*)d_in[2];
    const float* W2 = (const float*)d_in[3];
    const float* W3 = (const float*)d_in[4];
    float* y = (float*)d_out;
    char* ws = (char*)d_ws;

    unsigned short* xg = (unsigned short*)(ws + OFF_XG);
    unsigned short* U  = (unsigned short*)(ws + OFF_U);
    int*   stok   = (int*)(ws + OFF_STOK);
    float* sw     = (float*)(ws + OFF_SW);
    int*   counts = (int*)(ws + OFF_META);

    hipMemsetAsync(counts, 0, 64, stream);
    hipMemsetAsync(y, 0, (size_t)T_TOK * D_DIM * sizeof(float), stream);

    k_gate2<<<T_TOK / 4, 256, 0, stream>>>(x, Wg, stok, sw, counts, xg);
    k_gemm13<<<dim3(H_DIM / 32, CAP / 256, E_NUM), 256, 0, stream>>>(xg, W1, W3, counts, U);
    k_gemm2<<<dim3(D_DIM / 64, CAP / 256, E_NUM), 256, 0, stream>>>(U, W2, counts, stok, sw, y);
}